// Round 7
// baseline (32.191 us; speedup 1.0000x reference)
//
#include <hip/hip_runtime.h>
#include <math.h>

// Sampler: iterative Gumbel-softmax relaxed top-k.
// att: [B=256, N=1024, M=4] f32; k=128; out: khot [B,N,M] f32.
// One WAVE per (b,m) column (64 lanes x 16 elems as 8 packed float2).
// Loop-carried chain is the limiter (128 serial softmax iterations);
// this version packs elementwise math into v_pk_* f32 ops and rotates the
// loop: {tree-sum -> 6xDPP -> readlane -> rcp -> kh fma -> w *= (1-w*rinv)^2}.
// w carries exp(2*ag - M0) exactly (verified R4-R6); no clamp needed.
// PRNG: JAX threefry2x32 key (0,42), partitionable: counter (0,i),
// bits = out0 ^ out1 (verified R4).

#define N_NODES 1024

typedef float f2 __attribute__((ext_vector_type(2)));

__device__ __forceinline__ unsigned rotl32(unsigned x, int r) {
  return (x << r) | (x >> (32 - r));
}

// JAX/Random123 Threefry-2x32, 20 rounds.
__device__ __forceinline__ void threefry2x32(unsigned k0, unsigned k1,
                                             unsigned& x0, unsigned& x1) {
  const unsigned ks0 = k0, ks1 = k1, ks2 = k0 ^ k1 ^ 0x1BD11BDAu;
  x0 += ks0; x1 += ks1;
  x0 += x1; x1 = rotl32(x1, 13); x1 ^= x0;
  x0 += x1; x1 = rotl32(x1, 15); x1 ^= x0;
  x0 += x1; x1 = rotl32(x1, 26); x1 ^= x0;
  x0 += x1; x1 = rotl32(x1, 6);  x1 ^= x0;
  x0 += ks1; x1 += ks2 + 1u;
  x0 += x1; x1 = rotl32(x1, 17); x1 ^= x0;
  x0 += x1; x1 = rotl32(x1, 29); x1 ^= x0;
  x0 += x1; x1 = rotl32(x1, 16); x1 ^= x0;
  x0 += x1; x1 = rotl32(x1, 24); x1 ^= x0;
  x0 += ks2; x1 += ks0 + 2u;
  x0 += x1; x1 = rotl32(x1, 13); x1 ^= x0;
  x0 += x1; x1 = rotl32(x1, 15); x1 ^= x0;
  x0 += x1; x1 = rotl32(x1, 26); x1 ^= x0;
  x0 += x1; x1 = rotl32(x1, 6);  x1 ^= x0;
  x0 += ks0; x1 += ks1 + 3u;
  x0 += x1; x1 = rotl32(x1, 17); x1 ^= x0;
  x0 += x1; x1 = rotl32(x1, 29); x1 ^= x0;
  x0 += x1; x1 = rotl32(x1, 16); x1 ^= x0;
  x0 += x1; x1 = rotl32(x1, 24); x1 ^= x0;
  x0 += ks1; x1 += ks2 + 4u;
  x0 += x1; x1 = rotl32(x1, 13); x1 ^= x0;
  x0 += x1; x1 = rotl32(x1, 15); x1 ^= x0;
  x0 += x1; x1 = rotl32(x1, 26); x1 ^= x0;
  x0 += x1; x1 = rotl32(x1, 6);  x1 ^= x0;
  x0 += ks2; x1 += ks0 + 5u;
}

// --- DPP wave-64 reductions (VALU-rate; no LDS) ------------------------------
template <int CTRL>
__device__ __forceinline__ float dpp_sum_step(float v) {
  int t = __builtin_amdgcn_update_dpp(0, __float_as_int(v), CTRL, 0xf, 0xf, true);
  return v + __int_as_float(t);
}
template <int CTRL>
__device__ __forceinline__ float dpp_max_step(float v) {
  int iv = __float_as_int(v);
  int t = __builtin_amdgcn_update_dpp(iv, iv, CTRL, 0xf, 0xf, false);
  return fmaxf(v, __int_as_float(t));
}

__device__ __forceinline__ float wave_sum64(float v) {
  v = dpp_sum_step<0x111>(v);  // row_shr:1
  v = dpp_sum_step<0x112>(v);  // row_shr:2
  v = dpp_sum_step<0x114>(v);  // row_shr:4
  v = dpp_sum_step<0x118>(v);  // row_shr:8
  v = dpp_sum_step<0x142>(v);  // row_bcast:15
  v = dpp_sum_step<0x143>(v);  // row_bcast:31 -> lane 63 has full sum
  return __int_as_float(__builtin_amdgcn_readlane(__float_as_int(v), 63));
}
__device__ __forceinline__ float wave_max64(float v) {
  v = dpp_max_step<0x111>(v);
  v = dpp_max_step<0x112>(v);
  v = dpp_max_step<0x114>(v);
  v = dpp_max_step<0x118>(v);
  v = dpp_max_step<0x142>(v);
  v = dpp_max_step<0x143>(v);
  return __int_as_float(__builtin_amdgcn_readlane(__float_as_int(v), 63));
}

__global__ __launch_bounds__(64)
void Sampler_72619307040792_kernel(const float* __restrict__ att,
                                   const int* __restrict__ kp,
                                   float* __restrict__ out) {
  const int col = blockIdx.x;        // 0..1023 = b*4 + m; ONE wave per column
  const int b = col >> 2;
  const int m = col & 3;
  const int lane = threadIdx.x;      // 64 threads = 1 wave
  const int k = *kp;

  const float EPS = __uint_as_float(0x00800000u);  // f32 tiny (normal min)
  const int base = b * 4096 + m;     // + n*4 indexes element n of this column

  float g[16];
  f2 w[8], kh[8];

  // --- init: att + Gumbel noise (threefry partitionable, bits = x0^x1), x2
#pragma unroll
  for (int j = 0; j < 16; ++j) {
    const int n = j * 64 + lane;
    const unsigned idx = (unsigned)(base + n * 4);
    unsigned c0 = 0u, c1 = idx;
    threefry2x32(0u, 42u, c0, c1);
    const unsigned bits = c0 ^ c1;
    const float u = __uint_as_float((bits >> 9) | 0x3F800000u) - 1.0f;
    const float gum = -logf(-logf(u + EPS));
    g[j] = 2.0f * (att[idx] + gum);
  }

  // --- column max M0 (uniform shift; exact softmax equivalence)
  float mx = g[0];
#pragma unroll
  for (int j = 1; j < 16; ++j) mx = fmaxf(mx, g[j]);
  mx = wave_max64(mx);

  // --- w = exp(g - M0) packed; kh = 0
#pragma unroll
  for (int p = 0; p < 8; ++p) {
    f2 t;
    t.x = expf(g[2 * p] - mx);
    t.y = expf(g[2 * p + 1] - mx);
    w[p] = t;
    kh[p] = (f2)(0.0f);
  }

  // --- k iterations (rotated): S=sum w; rinv; kh += w*rinv; w *= (1-w*rinv)^2
  const f2 one = (f2)(1.0f);
  for (int it = 0; it < k; ++it) {
    // in-lane tree: 8 f2 -> 1 f2 (3 packed levels) -> scalar fold
    f2 s0 = w[0] + w[1];
    f2 s1 = w[2] + w[3];
    f2 s2 = w[4] + w[5];
    f2 s3 = w[6] + w[7];
    f2 sA = s0 + s1;
    f2 sB = s2 + s3;
    f2 sC = sA + sB;
    float sv = sC.x + sC.y;
    // cross-lane: 6 DPP + readlane(63); rcp straight off the SGPR
    const float S = wave_sum64(sv);
    const float rinv = __builtin_amdgcn_rcpf(S);
    f2 rv;
    rv.x = rinv;
    rv.y = rinv;
    // kh += w*rinv (old w), then w <- w*(1-w*rinv)^2
#pragma unroll
    for (int p = 0; p < 8; ++p)
      kh[p] = __builtin_elementwise_fma(w[p], rv, kh[p]);
#pragma unroll
    for (int p = 0; p < 8; ++p) {
      const f2 u = __builtin_elementwise_fma(-w[p], rv, one);
      const f2 t = w[p] * u;
      w[p] = t * u;
    }
  }

  // --- store khot
#pragma unroll
  for (int p = 0; p < 8; ++p) {
    out[base + (2 * p * 64 + lane) * 4] = kh[p].x;
    out[base + ((2 * p + 1) * 64 + lane) * 4] = kh[p].y;
  }
}

extern "C" void kernel_launch(void* const* d_in, const int* in_sizes, int n_in,
                              void* d_out, int out_size, void* d_ws, size_t ws_size,
                              hipStream_t stream) {
  const float* att = (const float*)d_in[0];
  const int* kp = (const int*)d_in[1];
  float* out = (float*)d_out;
  const int cols = out_size / N_NODES;  // 1024 columns, one wave each
  Sampler_72619307040792_kernel<<<cols, 64, 0, stream>>>(att, kp, out);
}